// Round 9
// baseline (270.763 us; speedup 1.0000x reference)
//
#include <hip/hip_runtime.h>
#include <hip/hip_cooperative_groups.h>
#include <cstdint>
#include <cstddef>

namespace cg = cooperative_groups;

// ManualChebConv v9: ONE cooperative launch.
// Evidence (v1-v8 accounting): total ~= sum(kernel dur) + ~20-25us per launch.
// v8 = ~70-90us of kernels + 4 launches = 151us. Fix: fuse prep -> P2 -> P3/P4
// -> chebgemm into one hipLaunchCooperativeKernel with grid.sync() between
// phases (256 blocks x 512 thr, 64KB LDS, <=256 VGPR -> 1 block/CU resident).
// Phase bodies are verbatim v8 kernels; phase A's Y-build restructured to 1x
// x-reads. Fallback: if coop enqueue errors, run v8's 4-launch path.

typedef __attribute__((ext_vector_type(8))) short  frag_ab;  // 8 bf16
typedef __attribute__((ext_vector_type(4))) float  frag_cd;  // 4 fp32

constexpr int BN  = 512;
constexpr int FIN = 16;
constexpr int FOUT= 8;
constexpr int PG  = 64;            // Pcat g width (k=1..4)
constexpr int LDST= BN + 8;        // last-resort LDS stride
constexpr int ZBUF= 64 * LDST;

__device__ __forceinline__ uint16_t f2bf(float f) {
    uint32_t u = __builtin_bit_cast(uint32_t, f);
    u += 0x7FFFu + ((u >> 16) & 1u);
    return (uint16_t)(u >> 16);
}
__device__ __forceinline__ float bf2f(uint16_t h) {
    uint32_t u = ((uint32_t)h) << 16;
    return __builtin_bit_cast(float, u);
}

// Pcat: [mt(32)][g(64)][lane(64)][elem(8)], g = (k-1)*16 + kt
__device__ __forceinline__ size_t pfrag(int mt, int g, int lane) {
    return ((size_t)(mt * PG + g) * 64 + lane) * 8;
}
__device__ __forceinline__ size_t pelem(int k, int row, int col) {  // k in 1..4
    return pfrag(row >> 4, (k - 1) * 16 + (col >> 5),
                 ((col >> 3) & 3) * 16 + (row & 15)) + (col & 7);
}
__device__ __forceinline__ size_t lfrag16(int mt, int kt, int lane) {
    return ((size_t)(mt * 16 + kt) * 64 + lane) * 8;
}
__device__ __forceinline__ size_t aswz(int row, int k) {
    return lfrag16(row >> 4, k >> 5, ((k >> 3) & 3) * 16 + (row & 15)) + (k & 7);
}
// Yf: [jt16(512)][g(80)][lane][8], kappa = k*512+m
__device__ __forceinline__ size_t yfrag(int jt16, int g, int lane) {
    return ((size_t)(jt16 * 80 + g) * 64 + lane) * 8;
}

// ==================== the cooperative mega-kernel ====================
__global__ __launch_bounds__(512, 2)
void megak(const float* __restrict__ x, const float* __restrict__ Lf,
           const float* __restrict__ W, uint16_t* __restrict__ Pcat,
           uint16_t* __restrict__ Llo, uint16_t* __restrict__ P2lo,
           uint16_t* __restrict__ Yf, const float* __restrict__ bvec,
           float* __restrict__ out) {
    __shared__ float fbuf[16384];            // 64 KB (phase D only)
    cg::grid_group grid = cg::this_grid();
    const int tid  = threadIdx.x;
    const int gtid = blockIdx.x * 512 + tid; // 0..131071

    // -------- Phase A: Y build (half-frag per thread, 1x x reads) --------
    {
        int task = gtid >> 1, half = gtid & 1;
        int b    = task >> 6;
        int moct = task & 63;
        int jhi  = b >> 1;
        int jl0  = (b & 1) * 8;
        const float* xb = x + (size_t)b * (BN * FIN)
                            + (size_t)(moct * 8 + half * 4) * FIN;
        float xr[4][16];
#pragma unroll
        for (int r = 0; r < 4; ++r)
#pragma unroll
            for (int fi = 0; fi < 4; ++fi) {
                float4 u = *reinterpret_cast<const float4*>(xb + (size_t)r * FIN + fi * 4);
                xr[r][fi * 4 + 0] = u.x; xr[r][fi * 4 + 1] = u.y;
                xr[r][fi * 4 + 2] = u.z; xr[r][fi * 4 + 3] = u.w;
            }
#pragma unroll
        for (int k = 0; k < 5; ++k) {
            float a[8][4] = {};
#pragma unroll
            for (int f = 0; f < 16; ++f) {
                float x0 = xr[0][f], x1 = xr[1][f], x2 = xr[2][f], x3 = xr[3][f];
#pragma unroll
                for (int fo = 0; fo < 8; ++fo) {
                    float w = W[(k * 16 + f) * 8 + fo];   // wave-uniform
                    a[fo][0] += x0 * w; a[fo][1] += x1 * w;
                    a[fo][2] += x2 * w; a[fo][3] += x3 * w;
                }
            }
#pragma unroll
            for (int fo = 0; fo < 8; ++fo) {
                ushort4 o;
                o.x = f2bf(a[fo][0]); o.y = f2bf(a[fo][1]);
                o.z = f2bf(a[fo][2]); o.w = f2bf(a[fo][3]);
                *reinterpret_cast<ushort4*>(
                    Yf + yfrag(jhi, k * 16 + (moct >> 2), (moct & 3) * 16 + jl0 + fo)
                       + half * 4) = o;
            }
        }
    }
    // L hi/lo -> fragment order (first 32768 threads)
    if (gtid < 32768) {
        int t = gtid;
        int lane = t & 63, f = t >> 6;
        int mt = f >> 4, kt = f & 15;
        int row = mt * 16 + (lane & 15);
        int k0  = kt * 32 + (lane >> 4) * 8;
        const float4* p = reinterpret_cast<const float4*>(Lf + (size_t)row * BN + k0);
        float4 u0 = p[0], u1 = p[1];
        float v[8] = {u0.x, u0.y, u0.z, u0.w, u1.x, u1.y, u1.z, u1.w};
        frag_ab hi, lo;
#pragma unroll
        for (int j = 0; j < 8; ++j) {
            uint16_t h = f2bf(v[j]);
            hi[j] = (short)h;
            lo[j] = (short)f2bf(v[j] - bf2f(h));
        }
        *reinterpret_cast<frag_ab*>(Pcat + pfrag(mt, kt, lane)) = hi;   // k=1
        *reinterpret_cast<frag_ab*>(Llo + lfrag16(mt, kt, lane)) = lo;
    }
    grid.sync();

    // -------- Phase B: P2 = 2*L*L - I (hi/lo), 1024 wave-tiles --------
    {
        int wv = tid >> 6, lane = tid & 63;
        int lr = lane & 15, q = lane >> 4;
        if (blockIdx.x < 128) {
            int id = blockIdx.x * 8 + wv;        // 0..1023
            int to = id >> 5, jt = id & 31;
            frag_cd acc = {0.f, 0.f, 0.f, 0.f};
#pragma unroll
            for (int ks = 0; ks < 16; ++ks) {
                frag_ab ahi = *reinterpret_cast<const frag_ab*>(Pcat + pfrag(to, ks, lane));
                frag_ab alo = *reinterpret_cast<const frag_ab*>(Llo + lfrag16(to, ks, lane));
                frag_ab bhi = *reinterpret_cast<const frag_ab*>(Pcat + pfrag(jt, ks, lane));
                frag_ab blo = *reinterpret_cast<const frag_ab*>(Llo + lfrag16(jt, ks, lane));
                acc = __builtin_amdgcn_mfma_f32_16x16x32_bf16(ahi, bhi, acc, 0, 0, 0);
                acc = __builtin_amdgcn_mfma_f32_16x16x32_bf16(alo, bhi, acc, 0, 0, 0);
                acc = __builtin_amdgcn_mfma_f32_16x16x32_bf16(ahi, blo, acc, 0, 0, 0);
            }
#pragma unroll
            for (int r = 0; r < 4; ++r) {
                int row = to * 16 + q * 4 + r, col = jt * 16 + lr;
                float v = 2.f * acc[r] - ((row == col) ? 1.f : 0.f);
                uint16_t h = f2bf(v);
                Pcat[pelem(2, row, col)] = h;
                P2lo[aswz(row, col)] = f2bf(v - bf2f(h));
            }
        }
    }
    grid.sync();

    // -------- Phase C: P3 = 2*L*P2 - L, P4 = 2*P2*P2 - I (2048 wave-tiles) --
    {
        int wv = tid >> 6, lane = tid & 63;
        int lr = lane & 15, q = lane >> 4;
        int id = blockIdx.x * 8 + wv;            // 0..2047
        bool isP3 = id < 1024;
        int id2 = isP3 ? id : id - 1024;
        int to = id2 >> 5, jt = id2 & 31;
        int agoff = isP3 ? 0 : 16;
        const uint16_t* aLo = isP3 ? Llo : P2lo;
        frag_cd acc = {0.f, 0.f, 0.f, 0.f};
#pragma unroll
        for (int ks = 0; ks < 16; ++ks) {
            frag_ab ahi = *reinterpret_cast<const frag_ab*>(Pcat + pfrag(to, agoff + ks, lane));
            frag_ab alo = *reinterpret_cast<const frag_ab*>(aLo + lfrag16(to, ks, lane));
            frag_ab bhi = *reinterpret_cast<const frag_ab*>(Pcat + pfrag(jt, 16 + ks, lane));
            frag_ab blo = *reinterpret_cast<const frag_ab*>(P2lo + lfrag16(jt, ks, lane));
            acc = __builtin_amdgcn_mfma_f32_16x16x32_bf16(ahi, bhi, acc, 0, 0, 0);
            acc = __builtin_amdgcn_mfma_f32_16x16x32_bf16(alo, bhi, acc, 0, 0, 0);
            acc = __builtin_amdgcn_mfma_f32_16x16x32_bf16(ahi, blo, acc, 0, 0, 0);
        }
#pragma unroll
        for (int r = 0; r < 4; ++r) {
            int row = to * 16 + q * 4 + r, col = jt * 16 + lr;
            if (isP3) {
                float sub = bf2f(Pcat[pelem(1, row, col)]) + bf2f(Llo[aswz(row, col)]);
                Pcat[pelem(3, row, col)] = f2bf(2.f * acc[r] - sub);
            } else {
                float sub = (row == col) ? 1.f : 0.f;
                Pcat[pelem(4, row, col)] = f2bf(2.f * acc[r] - sub);
            }
        }
    }
    grid.sync();

    // -------- Phase D: the GEMM (verbatim v8 chebgemm) --------
    {
        int bid = blockIdx.x;
        int xcd = bid & 7, n = bid >> 3;
        int jt  = xcd * 8 + (n >> 2);
        int mtB = n & 3;
        int wv = tid >> 6, lane = tid & 63;
        int lr = lane & 15, q = lane >> 4;
        int wm = wv >> 2, wj = wv & 3;

        frag_cd acc[4][2] = {};
#pragma unroll 2
        for (int kt = 0; kt < 64; ++kt) {
            frag_ab aF[4], bF[2];
#pragma unroll
            for (int mi = 0; mi < 4; ++mi)
                aF[mi] = *reinterpret_cast<const frag_ab*>(
                    Pcat + pfrag(mtB * 8 + wm * 4 + mi, kt, lane));
#pragma unroll
            for (int cj = 0; cj < 2; ++cj)
                bF[cj] = *reinterpret_cast<const frag_ab*>(
                    Yf + yfrag(jt * 8 + wj * 2 + cj, 16 + kt, lane));
#pragma unroll
            for (int mi = 0; mi < 4; ++mi)
#pragma unroll
                for (int cj = 0; cj < 2; ++cj)
                    acc[mi][cj] = __builtin_amdgcn_mfma_f32_16x16x32_bf16(
                        aF[mi], bF[cj], acc[mi][cj], 0, 0, 0);
        }
#pragma unroll
        for (int mi = 0; mi < 4; ++mi)
#pragma unroll
            for (int cj = 0; cj < 2; ++cj) {
                int jt16 = jt * 8 + wj * 2 + cj;
#pragma unroll
                for (int r = 0; r < 4; ++r) {
                    int nloc = wm * 64 + mi * 16 + q * 4 + r;
                    int ng = mtB * 128 + nloc;
                    float y0 = bf2f(Yf[yfrag(jt16, ng >> 5, ((ng >> 3) & 3) * 16 + lr)
                                       + (ng & 7)]);
                    fbuf[nloc * 128 + wj * 32 + cj * 16 + lr] = acc[mi][cj][r] + y0;
                }
            }
        __syncthreads();
        float4 bv0 = *reinterpret_cast<const float4*>(bvec);
        float4 bv1 = *(reinterpret_cast<const float4*>(bvec) + 1);
#pragma unroll
        for (int i = 0; i < 8; ++i) {
            int idx = i * 2048 + tid * 4;
            int bb = idx >> 10, r = idx & 1023, nn = r >> 3, fo = r & 7;
            float4 v = *reinterpret_cast<const float4*>(fbuf + nn * 128 + bb * 8 + fo);
            float4 bias = (fo & 4) ? bv1 : bv0;
            v.x += bias.x; v.y += bias.y; v.z += bias.z; v.w += bias.w;
            *reinterpret_cast<float4*>(out + (size_t)(jt * 16 + bb) * 4096
                                           + (size_t)(mtB * 128 + nn) * 8 + fo) = v;
        }
    }
}

// ==================== v8 standalone kernels (coop-enqueue fallback) ====================

__global__ __launch_bounds__(256)
void prep(const float* __restrict__ x, const float* __restrict__ Lf,
          const float* __restrict__ W, uint16_t* __restrict__ Pcat,
          uint16_t* __restrict__ Llo, uint16_t* __restrict__ Yf) {
    int bid = blockIdx.x, tid = threadIdx.x;
    if (bid < 2048) {
        int t = bid * 256 + tid;
        int jlow = t & 15;
        int moct = (t >> 4) & 63;
        int jhi  = t >> 10;
        int b  = jhi * 2 + (jlow >> 3);
        int fo = jlow & 7;
        int m0 = moct * 8;
        float wr[5][16];
#pragma unroll
        for (int k = 0; k < 5; ++k)
#pragma unroll
            for (int f = 0; f < 16; ++f)
                wr[k][f] = W[(k * 16 + f) * 8 + fo];
        float tmp[5][8];
        const float* xb = x + (size_t)b * (BN * FIN) + (size_t)m0 * FIN;
#pragma unroll
        for (int r = 0; r < 8; ++r) {
            float xr[16];
#pragma unroll
            for (int fi = 0; fi < 4; ++fi) {
                float4 u = *reinterpret_cast<const float4*>(xb + r * FIN + fi * 4);
                xr[fi * 4 + 0] = u.x; xr[fi * 4 + 1] = u.y;
                xr[fi * 4 + 2] = u.z; xr[fi * 4 + 3] = u.w;
            }
#pragma unroll
            for (int k = 0; k < 5; ++k) {
                float s = 0.f;
#pragma unroll
                for (int f = 0; f < 16; ++f) s += xr[f] * wr[k][f];
                tmp[k][r] = s;
            }
        }
#pragma unroll
        for (int k = 0; k < 5; ++k) {
            frag_ab o;
#pragma unroll
            for (int j = 0; j < 8; ++j) o[j] = (short)f2bf(tmp[k][j]);
            *reinterpret_cast<frag_ab*>(
                Yf + yfrag(jhi, k * 16 + (moct >> 2), (moct & 3) * 16 + jlow)) = o;
        }
    } else {
        int t = (bid - 2048) * 256 + tid;
        int lane = t & 63, f = t >> 6;
        int mt = f >> 4, kt = f & 15;
        int row = mt * 16 + (lane & 15);
        int k0  = kt * 32 + (lane >> 4) * 8;
        const float4* p = reinterpret_cast<const float4*>(Lf + (size_t)row * BN + k0);
        float4 u0 = p[0], u1 = p[1];
        float v[8] = {u0.x, u0.y, u0.z, u0.w, u1.x, u1.y, u1.z, u1.w};
        frag_ab hi, lo;
#pragma unroll
        for (int j = 0; j < 8; ++j) {
            uint16_t h = f2bf(v[j]);
            hi[j] = (short)h;
            lo[j] = (short)f2bf(v[j] - bf2f(h));
        }
        *reinterpret_cast<frag_ab*>(Pcat + pfrag(mt, kt, lane)) = hi;
        *reinterpret_cast<frag_ab*>(Llo + lfrag16(mt, kt, lane)) = lo;
    }
}

__global__ __launch_bounds__(512)
void p2k(uint16_t* __restrict__ Pcat, const uint16_t* __restrict__ Llo,
         uint16_t* __restrict__ P2lo) {
    int tid = threadIdx.x, wv = tid >> 6, lane = tid & 63;
    int lr = lane & 15, q = lane >> 4;
    int id = blockIdx.x * 8 + wv;
    int to = id >> 5, jt = id & 31;
    frag_cd acc = {0.f, 0.f, 0.f, 0.f};
#pragma unroll
    for (int ks = 0; ks < 16; ++ks) {
        frag_ab ahi = *reinterpret_cast<const frag_ab*>(Pcat + pfrag(to, ks, lane));
        frag_ab alo = *reinterpret_cast<const frag_ab*>(Llo + lfrag16(to, ks, lane));
        frag_ab bhi = *reinterpret_cast<const frag_ab*>(Pcat + pfrag(jt, ks, lane));
        frag_ab blo = *reinterpret_cast<const frag_ab*>(Llo + lfrag16(jt, ks, lane));
        acc = __builtin_amdgcn_mfma_f32_16x16x32_bf16(ahi, bhi, acc, 0, 0, 0);
        acc = __builtin_amdgcn_mfma_f32_16x16x32_bf16(alo, bhi, acc, 0, 0, 0);
        acc = __builtin_amdgcn_mfma_f32_16x16x32_bf16(ahi, blo, acc, 0, 0, 0);
    }
#pragma unroll
    for (int r = 0; r < 4; ++r) {
        int row = to * 16 + q * 4 + r, col = jt * 16 + lr;
        float v = 2.f * acc[r] - ((row == col) ? 1.f : 0.f);
        uint16_t h = f2bf(v);
        Pcat[pelem(2, row, col)] = h;
        P2lo[aswz(row, col)] = f2bf(v - bf2f(h));
    }
}

__global__ __launch_bounds__(512)
void p34k(uint16_t* __restrict__ Pcat, const uint16_t* __restrict__ Llo,
          const uint16_t* __restrict__ P2lo) {
    int tid = threadIdx.x, wv = tid >> 6, lane = tid & 63;
    int lr = lane & 15, q = lane >> 4;
    int id = blockIdx.x * 8 + wv;
    bool isP3 = id < 1024;
    int id2 = isP3 ? id : id - 1024;
    int to = id2 >> 5, jt = id2 & 31;
    int agoff = isP3 ? 0 : 16;
    const uint16_t* aLo = isP3 ? Llo : P2lo;
    frag_cd acc = {0.f, 0.f, 0.f, 0.f};
#pragma unroll
    for (int ks = 0; ks < 16; ++ks) {
        frag_ab ahi = *reinterpret_cast<const frag_ab*>(Pcat + pfrag(to, agoff + ks, lane));
        frag_ab alo = *reinterpret_cast<const frag_ab*>(aLo + lfrag16(to, ks, lane));
        frag_ab bhi = *reinterpret_cast<const frag_ab*>(Pcat + pfrag(jt, 16 + ks, lane));
        frag_ab blo = *reinterpret_cast<const frag_ab*>(P2lo + lfrag16(jt, ks, lane));
        acc = __builtin_amdgcn_mfma_f32_16x16x32_bf16(ahi, bhi, acc, 0, 0, 0);
        acc = __builtin_amdgcn_mfma_f32_16x16x32_bf16(alo, bhi, acc, 0, 0, 0);
        acc = __builtin_amdgcn_mfma_f32_16x16x32_bf16(ahi, blo, acc, 0, 0, 0);
    }
#pragma unroll
    for (int r = 0; r < 4; ++r) {
        int row = to * 16 + q * 4 + r, col = jt * 16 + lr;
        if (isP3) {
            float sub = bf2f(Pcat[pelem(1, row, col)]) + bf2f(Llo[aswz(row, col)]);
            Pcat[pelem(3, row, col)] = f2bf(2.f * acc[r] - sub);
        } else {
            float sub = (row == col) ? 1.f : 0.f;
            Pcat[pelem(4, row, col)] = f2bf(2.f * acc[r] - sub);
        }
    }
}

__global__ __launch_bounds__(512)
void chebgemm(const uint16_t* __restrict__ Pcat, const uint16_t* __restrict__ Yf,
              const float* __restrict__ bvec, float* __restrict__ out) {
    __shared__ float fbuf[16384];
    int bid = blockIdx.x;
    int xcd = bid & 7, n = bid >> 3;
    int jt  = xcd * 8 + (n >> 2);
    int mtB = n & 3;
    int tid = threadIdx.x, wv = tid >> 6, lane = tid & 63;
    int lr = lane & 15, q = lane >> 4;
    int wm = wv >> 2, wj = wv & 3;

    frag_cd acc[4][2] = {};
#pragma unroll 2
    for (int kt = 0; kt < 64; ++kt) {
        frag_ab aF[4], bF[2];
#pragma unroll
        for (int mi = 0; mi < 4; ++mi)
            aF[mi] = *reinterpret_cast<const frag_ab*>(
                Pcat + pfrag(mtB * 8 + wm * 4 + mi, kt, lane));
#pragma unroll
        for (int cj = 0; cj < 2; ++cj)
            bF[cj] = *reinterpret_cast<const frag_ab*>(
                Yf + yfrag(jt * 8 + wj * 2 + cj, 16 + kt, lane));
#pragma unroll
        for (int mi = 0; mi < 4; ++mi)
#pragma unroll
            for (int cj = 0; cj < 2; ++cj)
                acc[mi][cj] = __builtin_amdgcn_mfma_f32_16x16x32_bf16(
                    aF[mi], bF[cj], acc[mi][cj], 0, 0, 0);
    }
#pragma unroll
    for (int mi = 0; mi < 4; ++mi)
#pragma unroll
        for (int cj = 0; cj < 2; ++cj) {
            int jt16 = jt * 8 + wj * 2 + cj;
#pragma unroll
            for (int r = 0; r < 4; ++r) {
                int nloc = wm * 64 + mi * 16 + q * 4 + r;
                int ng = mtB * 128 + nloc;
                float y0 = bf2f(Yf[yfrag(jt16, ng >> 5, ((ng >> 3) & 3) * 16 + lr)
                                   + (ng & 7)]);
                fbuf[nloc * 128 + wj * 32 + cj * 16 + lr] = acc[mi][cj][r] + y0;
            }
        }
    __syncthreads();
    float4 bv0 = *reinterpret_cast<const float4*>(bvec);
    float4 bv1 = *(reinterpret_cast<const float4*>(bvec) + 1);
#pragma unroll
    for (int i = 0; i < 8; ++i) {
        int idx = i * 2048 + tid * 4;
        int bb = idx >> 10, r = idx & 1023, nn = r >> 3, fo = r & 7;
        float4 v = *reinterpret_cast<const float4*>(fbuf + nn * 128 + bb * 8 + fo);
        float4 bias = (fo & 4) ? bv1 : bv0;
        v.x += bias.x; v.y += bias.y; v.z += bias.z; v.w += bias.w;
        *reinterpret_cast<float4*>(out + (size_t)(jt * 16 + bb) * 4096
                                       + (size_t)(mtB * 128 + nn) * 8 + fo) = v;
    }
}

// ---------------- last resort (tiny workspace): direct recurrence ----------------
__global__ __launch_bounds__(512, 2)
void cheb1_kernel(const float* __restrict__ x, const float* __restrict__ Lf,
                  const float* __restrict__ W, const float* __restrict__ bvec,
                  float* __restrict__ out) {
    __shared__ uint16_t ldsb[2 * ZBUF];
    uint16_t* z0 = ldsb;
    uint16_t* z1 = ldsb + ZBUF;
    const int tid = threadIdx.x, wave = tid >> 6, lane = tid & 63;
    const int lr = lane & 15, q = lane >> 4;
    const float4* x4 = reinterpret_cast<const float4*>(x + (size_t)blockIdx.x * (4 * BN * FIN));
    for (int s = 0; s < 2; ++s) {
        int a = tid + s * 512;
        int f0g = a & 3, n8 = (a >> 2) & 63, bl = a >> 8;
        int jb = bl * 2048 + n8 * 32 + f0g;
        float4 v[8];
#pragma unroll
        for (int r = 0; r < 8; ++r) v[r] = x4[jb + r * 4];
        int cb = bl * 16 + f0g * 4, nb = n8 * 8;
#pragma unroll
        for (int w = 0; w < 4; ++w) {
            frag_ab pk;
#pragma unroll
            for (int r = 0; r < 8; ++r)
                pk[r] = (short)f2bf(reinterpret_cast<const float*>(&v[r])[w]);
            *reinterpret_cast<frag_ab*>(&z0[(cb + w) * LDST + nb]) = pk;
        }
    }
    frag_ab wf[3];
#pragma unroll
    for (int p = 0; p < 3; ++p) {
        frag_ab t;
#pragma unroll
        for (int jj = 0; jj < 8; ++jj) {
            int k = q * 8 + jj, ki = p * 2 + (k >> 4), fin = k & 15;
            float val = (lr < 8 && ki < 5) ? W[ki * 128 + fin * FOUT + lr] : 0.0f;
            t[jj] = (short)f2bf(val);
        }
        wf[p] = t;
    }
    const float bv = (lr < 8) ? bvec[lr] : 0.0f;
    frag_cd accOut[4][4] = {};
    auto loadA = [&](int mt, int ks) -> frag_ab {
        const float4* p = reinterpret_cast<const float4*>(Lf + (size_t)(mt * 16 + lr) * BN + ks * 32 + q * 8);
        float4 u0 = p[0], u1 = p[1];
        frag_ab t;
        t[0] = (short)f2bf(u0.x); t[1] = (short)f2bf(u0.y);
        t[2] = (short)f2bf(u0.z); t[3] = (short)f2bf(u0.w);
        t[4] = (short)f2bf(u1.x); t[5] = (short)f2bf(u1.y);
        t[6] = (short)f2bf(u1.z); t[7] = (short)f2bf(u1.w);
        return t;
    };
    auto app = [&](const uint16_t* cur, uint16_t* dst, bool first) {
        frag_cd acc[4][4] = {};
        for (int ks = 0; ks < 16; ++ks) {
            frag_ab bfr[4];
#pragma unroll
            for (int ct = 0; ct < 4; ++ct)
                bfr[ct] = *reinterpret_cast<const frag_ab*>(
                    cur + (ct * 16 + lr) * LDST + ks * 32 + q * 8);
#pragma unroll
            for (int mi = 0; mi < 4; ++mi) {
                frag_ab a = loadA(wave + mi * 8, ks);
#pragma unroll
                for (int ct = 0; ct < 4; ++ct)
                    acc[mi][ct] = __builtin_amdgcn_mfma_f32_16x16x32_bf16(
                        a, bfr[ct], acc[mi][ct], 0, 0, 0);
            }
        }
#pragma unroll
        for (int mi = 0; mi < 4; ++mi) {
            int row0 = (wave + mi * 8) * 16 + q * 4;
#pragma unroll
            for (int ct = 0; ct < 4; ++ct) {
                uint16_t* dp = dst + (ct * 16 + lr) * LDST + row0;
                float pz[4] = {0.f, 0.f, 0.f, 0.f};
                if (!first) {
                    ushort4 pv = *reinterpret_cast<const ushort4*>(dp);
                    pz[0] = bf2f(pv.x); pz[1] = bf2f(pv.y);
                    pz[2] = bf2f(pv.z); pz[3] = bf2f(pv.w);
                }
                ushort4 nv;
                float v0 = acc[mi][ct][0], v1 = acc[mi][ct][1];
                float v2 = acc[mi][ct][2], v3 = acc[mi][ct][3];
                if (!first) { v0 = 2.f*v0-pz[0]; v1 = 2.f*v1-pz[1];
                              v2 = 2.f*v2-pz[2]; v3 = 2.f*v3-pz[3]; }
                nv.x = f2bf(v0); nv.y = f2bf(v1); nv.z = f2bf(v2); nv.w = f2bf(v3);
                *reinterpret_cast<ushort4*>(dp) = nv;
            }
        }
    };
    auto epi = [&](const uint16_t* bA, const uint16_t* bB, frag_ab wfr) {
        const uint16_t* base = (q < 2) ? bA : bB;
        int finb = (q & 1) * 8;
#pragma unroll
        for (int mi = 0; mi < 4; ++mi) {
            int n = (wave + mi * 8) * 16 + lr;
#pragma unroll
            for (int bt = 0; bt < 4; ++bt) {
                const uint16_t* pp = base + (bt * 16 + finb) * LDST + n;
                frag_ab afr;
#pragma unroll
                for (int jj = 0; jj < 8; ++jj) afr[jj] = (short)pp[jj * LDST];
                accOut[mi][bt] = __builtin_amdgcn_mfma_f32_16x16x32_bf16(
                    afr, wfr, accOut[mi][bt], 0, 0, 0);
            }
        }
    };
    __syncthreads();
    app(z0, z1, true);  __syncthreads();
    epi(z0, z1, wf[0]); __syncthreads();
    app(z1, z0, false); __syncthreads();
    app(z0, z1, false); __syncthreads();
    epi(z0, z1, wf[1]); __syncthreads();
    app(z1, z0, false); __syncthreads();
    epi(z0, z0, wf[2]);
    if (lr < 8) {
        float* ob = out + (size_t)blockIdx.x * 4 * BN * FOUT;
#pragma unroll
        for (int mi = 0; mi < 4; ++mi) {
            int row0 = (wave + mi * 8) * 16 + q * 4;
#pragma unroll
            for (int bt = 0; bt < 4; ++bt) {
                float* op = ob + bt * (BN * FOUT) + row0 * FOUT + lr;
                op[0] = accOut[mi][bt][0] + bv; op[FOUT] = accOut[mi][bt][1] + bv;
                op[2 * FOUT] = accOut[mi][bt][2] + bv; op[3 * FOUT] = accOut[mi][bt][3] + bv;
            }
        }
    }
}

extern "C" void kernel_launch(void* const* d_in, const int* in_sizes, int n_in,
                              void* d_out, int out_size, void* d_ws, size_t ws_size,
                              hipStream_t stream) {
    const float* x  = (const float*)d_in[0];   // [1024,512,16]
    const float* Lf = (const float*)d_in[1];   // [512,512]
    const float* W  = (const float*)d_in[2];   // [5,16,8]
    const float* bv = (const float*)d_in[3];   // [8]
    float* out = (float*)d_out;                // [1024,512,8]

    const size_t PCAT_B = (size_t)32 * PG * 64 * 8 * 2;    //  2,097,152
    const size_t LLO_B  = (size_t)BN * BN * 2;             //    524,288
    const size_t P2LO_B = LLO_B;                           //    524,288
    const size_t YF_B   = (size_t)512 * 80 * 64 * 8 * 2;   // 41,943,040

    if (ws_size >= PCAT_B + LLO_B + P2LO_B + YF_B) {       // 45,088,768 (v8 req)
        uint16_t* Pcat = (uint16_t*)d_ws;
        uint16_t* Llo  = Pcat + PCAT_B / 2;
        uint16_t* P2lo = Pcat + (PCAT_B + LLO_B) / 2;
        uint16_t* Yf   = Pcat + (PCAT_B + LLO_B + P2LO_B) / 2;

        void* kargs[] = {(void*)&x, (void*)&Lf, (void*)&W, (void*)&Pcat,
                         (void*)&Llo, (void*)&P2lo, (void*)&Yf, (void*)&bv,
                         (void*)&out};
        hipError_t ce = hipLaunchCooperativeKernel(
            (const void*)megak, dim3(256), dim3(512), kargs, 0, stream);
        if (ce != hipSuccess) {
            (void)hipGetLastError();               // clear sticky error
            // v8 4-launch path (verified @151us)
            prep    <<<dim3(2176), dim3(256), 0, stream>>>(x, Lf, W, Pcat, Llo, Yf);
            p2k     <<<dim3(128),  dim3(512), 0, stream>>>(Pcat, Llo, P2lo);
            p34k    <<<dim3(256),  dim3(512), 0, stream>>>(Pcat, Llo, P2lo);
            chebgemm<<<dim3(256),  dim3(512), 0, stream>>>(Pcat, Yf, bv, out);
        }
    } else {
        cheb1_kernel<<<dim3(256), dim3(512), 0, stream>>>(x, Lf, W, bv, out);
    }
}

// Round 10
// 149.631 us; speedup vs baseline: 1.8095x; 1.8095x over previous
//
#include <hip/hip_runtime.h>
#include <cstdint>
#include <cstddef>

// ManualChebConv v10: 3-launch single-GEMM pipeline.
//   K1 prepP2 : Yf build (1x x reads) | L -> Pcat(k=1)+Llo | P2 from Lf direct
//   K2 p34k   : P3 = 2*L*P2 - L, P4 = 2*P2*P2 - I
//   K3 chebgemm: out = Y0 + Pcat(k=1..4) @ Yf + bias, 1024 thr (4 waves/SIMD)
// Post-mortems: v9 coop grid.sync ~= 40us each + cold L2 -> reverted.
// Corrected accounting: gaps ~18us/launch; v8 prep read x 8x (~20us);
// chebgemm idle at 2 waves/SIMD. v10: -1 launch, 1x x reads, 2x TLP in GEMM
// (acc is only 16 VGPR at 32x32 wave tile -> no spill risk, unlike v5/v6).

typedef __attribute__((ext_vector_type(8))) short  frag_ab;  // 8 bf16
typedef __attribute__((ext_vector_type(4))) float  frag_cd;  // 4 fp32

constexpr int BN  = 512;
constexpr int FIN = 16;
constexpr int FOUT= 8;
constexpr int PG  = 64;            // Pcat g width (k=1..4)
constexpr int LDST= BN + 8;        // last-resort LDS stride
constexpr int ZBUF= 64 * LDST;

__device__ __forceinline__ uint16_t f2bf(float f) {
    uint32_t u = __builtin_bit_cast(uint32_t, f);
    u += 0x7FFFu + ((u >> 16) & 1u);
    return (uint16_t)(u >> 16);
}
__device__ __forceinline__ float bf2f(uint16_t h) {
    uint32_t u = ((uint32_t)h) << 16;
    return __builtin_bit_cast(float, u);
}

// Pcat: [mt(32)][g(64)][lane(64)][elem(8)], g = (k-1)*16 + kt
__device__ __forceinline__ size_t pfrag(int mt, int g, int lane) {
    return ((size_t)(mt * PG + g) * 64 + lane) * 8;
}
__device__ __forceinline__ size_t pelem(int k, int row, int col) {  // k in 1..4
    return pfrag(row >> 4, (k - 1) * 16 + (col >> 5),
                 ((col >> 3) & 3) * 16 + (row & 15)) + (col & 7);
}
__device__ __forceinline__ size_t lfrag16(int mt, int kt, int lane) {
    return ((size_t)(mt * 16 + kt) * 64 + lane) * 8;
}
__device__ __forceinline__ size_t aswz(int row, int k) {
    return lfrag16(row >> 4, k >> 5, ((k >> 3) & 3) * 16 + (row & 15)) + (k & 7);
}
// Yf: [jt16(512)][g(80)][lane][8], kappa = k*512+m
__device__ __forceinline__ size_t yfrag(int jt16, int g, int lane) {
    return ((size_t)(jt16 * 80 + g) * 64 + lane) * 8;
}

// ---------------- K1: Yf build + L conversion + P2 (independent roles) ----------------
// blocks [0,512): Yf (131072 threads, one half-fragment each, 1x x reads)
// blocks [512,640): L -> Pcat(k=1) hi + Llo
// blocks [640,896): P2 = 2*L*L - I from fp32 Lf (m2comp-style, v3-verified)
__global__ __launch_bounds__(256)
void prepP2(const float* __restrict__ x, const float* __restrict__ Lf,
            const float* __restrict__ W, uint16_t* __restrict__ Pcat,
            uint16_t* __restrict__ Llo, uint16_t* __restrict__ P2lo,
            uint16_t* __restrict__ Yf) {
    const int bid = blockIdx.x, tid = threadIdx.x;
    if (bid < 512) {
        // ---- Y build (verbatim v9 phase A, correctness-verified) ----
        int gtid = bid * 256 + tid;              // 0..131071
        int task = gtid >> 1, half = gtid & 1;
        int b    = task >> 6;
        int moct = task & 63;
        int jhi  = b >> 1;
        int jl0  = (b & 1) * 8;
        const float* xb = x + (size_t)b * (BN * FIN)
                            + (size_t)(moct * 8 + half * 4) * FIN;
        float xr[4][16];
#pragma unroll
        for (int r = 0; r < 4; ++r)
#pragma unroll
            for (int fi = 0; fi < 4; ++fi) {
                float4 u = *reinterpret_cast<const float4*>(xb + (size_t)r * FIN + fi * 4);
                xr[r][fi * 4 + 0] = u.x; xr[r][fi * 4 + 1] = u.y;
                xr[r][fi * 4 + 2] = u.z; xr[r][fi * 4 + 3] = u.w;
            }
#pragma unroll
        for (int k = 0; k < 5; ++k) {
            float a[8][4] = {};
#pragma unroll
            for (int f = 0; f < 16; ++f) {
                float x0 = xr[0][f], x1 = xr[1][f], x2 = xr[2][f], x3 = xr[3][f];
#pragma unroll
                for (int fo = 0; fo < 8; ++fo) {
                    float w = W[(k * 16 + f) * 8 + fo];   // wave-uniform
                    a[fo][0] += x0 * w; a[fo][1] += x1 * w;
                    a[fo][2] += x2 * w; a[fo][3] += x3 * w;
                }
            }
#pragma unroll
            for (int fo = 0; fo < 8; ++fo) {
                ushort4 o;
                o.x = f2bf(a[fo][0]); o.y = f2bf(a[fo][1]);
                o.z = f2bf(a[fo][2]); o.w = f2bf(a[fo][3]);
                *reinterpret_cast<ushort4*>(
                    Yf + yfrag(jhi, k * 16 + (moct >> 2), (moct & 3) * 16 + jl0 + fo)
                       + half * 4) = o;
            }
        }
    } else if (bid < 640) {
        // ---- L hi/lo -> fragment order ----
        int t = (bid - 512) * 256 + tid;         // 0..32767
        int lane = t & 63, f = t >> 6;
        int mt = f >> 4, kt = f & 15;
        int row = mt * 16 + (lane & 15);
        int k0  = kt * 32 + (lane >> 4) * 8;
        const float4* p = reinterpret_cast<const float4*>(Lf + (size_t)row * BN + k0);
        float4 u0 = p[0], u1 = p[1];
        float v[8] = {u0.x, u0.y, u0.z, u0.w, u1.x, u1.y, u1.z, u1.w};
        frag_ab hi, lo;
#pragma unroll
        for (int j = 0; j < 8; ++j) {
            uint16_t h = f2bf(v[j]);
            hi[j] = (short)h;
            lo[j] = (short)f2bf(v[j] - bf2f(h));
        }
        *reinterpret_cast<frag_ab*>(Pcat + pfrag(mt, kt, lane)) = hi;   // k=1
        *reinterpret_cast<frag_ab*>(Llo + lfrag16(mt, kt, lane)) = lo;
    } else {
        // ---- P2 = 2*L*L - I from fp32 Lf (v3 m2comp body) ----
        int pb = bid - 640;                      // 0..255
        int wv = tid >> 6, lane = tid & 63, lr = lane & 15, q = lane >> 4;
        int i0 = (pb >> 4) * 32 + (wv >> 1) * 16;
        int j0 = (pb & 15) * 32 + (wv & 1) * 16;
        frag_cd acc = {0.f, 0.f, 0.f, 0.f};
        const float* arow = Lf + (size_t)(i0 + lr) * BN;   // A[m][k] = L[i0+m][k]
        const float* brow = Lf + (size_t)(j0 + lr) * BN;   // B[k][n] = L[j0+n][k] (symmetric)
        for (int ks = 0; ks < 16; ++ks) {
            const int kb = ks * 32 + q * 8;
            const float4* ap = reinterpret_cast<const float4*>(arow + kb);
            const float4* bp = reinterpret_cast<const float4*>(brow + kb);
            float4 A0 = ap[0], A1 = ap[1], B0 = bp[0], B1 = bp[1];
            float av[8] = {A0.x, A0.y, A0.z, A0.w, A1.x, A1.y, A1.z, A1.w};
            float bw[8] = {B0.x, B0.y, B0.z, B0.w, B1.x, B1.y, B1.z, B1.w};
            frag_ab ah, al, bh, bl;
#pragma unroll
            for (int j = 0; j < 8; ++j) {
                uint16_t h = f2bf(av[j]);
                ah[j] = (short)h; al[j] = (short)f2bf(av[j] - bf2f(h));
                uint16_t g = f2bf(bw[j]);
                bh[j] = (short)g; bl[j] = (short)f2bf(bw[j] - bf2f(g));
            }
            acc = __builtin_amdgcn_mfma_f32_16x16x32_bf16(ah, bh, acc, 0, 0, 0);
            acc = __builtin_amdgcn_mfma_f32_16x16x32_bf16(al, bh, acc, 0, 0, 0);
            acc = __builtin_amdgcn_mfma_f32_16x16x32_bf16(ah, bl, acc, 0, 0, 0);
        }
#pragma unroll
        for (int r = 0; r < 4; ++r) {
            int row = i0 + q * 4 + r, col = j0 + lr;
            float v = 2.f * acc[r] - ((row == col) ? 1.f : 0.f);
            uint16_t h = f2bf(v);
            Pcat[pelem(2, row, col)] = h;
            P2lo[aswz(row, col)] = f2bf(v - bf2f(h));
        }
    }
}

// ---------------- K2: P3 = 2*L*P2 - L, P4 = 2*P2*P2 - I ----------------
__global__ __launch_bounds__(512)
void p34k(uint16_t* __restrict__ Pcat, const uint16_t* __restrict__ Llo,
          const uint16_t* __restrict__ P2lo) {
    int tid = threadIdx.x, wv = tid >> 6, lane = tid & 63;
    int lr = lane & 15, q = lane >> 4;
    int id = blockIdx.x * 8 + wv;                // 0..2047
    bool isP3 = id < 1024;
    int id2 = isP3 ? id : id - 1024;
    int to = id2 >> 5, jt = id2 & 31;
    int agoff = isP3 ? 0 : 16;
    const uint16_t* aLo = isP3 ? Llo : P2lo;
    frag_cd acc = {0.f, 0.f, 0.f, 0.f};
#pragma unroll
    for (int ks = 0; ks < 16; ++ks) {
        frag_ab ahi = *reinterpret_cast<const frag_ab*>(Pcat + pfrag(to, agoff + ks, lane));
        frag_ab alo = *reinterpret_cast<const frag_ab*>(aLo + lfrag16(to, ks, lane));
        frag_ab bhi = *reinterpret_cast<const frag_ab*>(Pcat + pfrag(jt, 16 + ks, lane));
        frag_ab blo = *reinterpret_cast<const frag_ab*>(P2lo + lfrag16(jt, ks, lane));
        acc = __builtin_amdgcn_mfma_f32_16x16x32_bf16(ahi, bhi, acc, 0, 0, 0);
        acc = __builtin_amdgcn_mfma_f32_16x16x32_bf16(alo, bhi, acc, 0, 0, 0);
        acc = __builtin_amdgcn_mfma_f32_16x16x32_bf16(ahi, blo, acc, 0, 0, 0);
    }
#pragma unroll
    for (int r = 0; r < 4; ++r) {
        int row = to * 16 + q * 4 + r, col = jt * 16 + lr;
        if (isP3) {
            float sub = bf2f(Pcat[pelem(1, row, col)]) + bf2f(Llo[aswz(row, col)]);
            Pcat[pelem(3, row, col)] = f2bf(2.f * acc[r] - sub);
        } else {
            float sub = (row == col) ? 1.f : 0.f;
            Pcat[pelem(4, row, col)] = f2bf(2.f * acc[r] - sub);
        }
    }
}

// ---------------- K3: the GEMM, 1024 threads (4 waves/SIMD) ----------------
// 256 blocks (1/CU), 16 waves (4M x 4J), wave tile 32x32 -> acc 2x2 (16 VGPR).
// Same 128x128 block tile and traffic as v8; doubled TLP.
__global__ __launch_bounds__(1024)
void chebgemm(const uint16_t* __restrict__ Pcat, const uint16_t* __restrict__ Yf,
              const float* __restrict__ bvec, float* __restrict__ out) {
    __shared__ float fbuf[16384];                // 64 KB epilogue stage
    int bid = blockIdx.x;
    int xcd = bid & 7, n = bid >> 3;
    int jt  = xcd * 8 + (n >> 2);                // 8 j-tiles per XCD
    int mtB = n & 3;
    int tid = threadIdx.x, wv = tid >> 6, lane = tid & 63;
    int lr = lane & 15, q = lane >> 4;
    int wm = wv >> 2, wj = wv & 3;               // 4 x 4 wave grid

    frag_cd acc[2][2] = {};
#pragma unroll 4
    for (int kt = 0; kt < 64; ++kt) {
        frag_ab aF[2], bF[2];
#pragma unroll
        for (int mi = 0; mi < 2; ++mi)
            aF[mi] = *reinterpret_cast<const frag_ab*>(
                Pcat + pfrag(mtB * 8 + wm * 2 + mi, kt, lane));
#pragma unroll
        for (int cj = 0; cj < 2; ++cj)
            bF[cj] = *reinterpret_cast<const frag_ab*>(
                Yf + yfrag(jt * 8 + wj * 2 + cj, 16 + kt, lane));
#pragma unroll
        for (int mi = 0; mi < 2; ++mi)
#pragma unroll
            for (int cj = 0; cj < 2; ++cj)
                acc[mi][cj] = __builtin_amdgcn_mfma_f32_16x16x32_bf16(
                    aF[mi], bF[cj], acc[mi][cj], 0, 0, 0);
    }
    // identity (k=0) term + stage to LDS
#pragma unroll
    for (int mi = 0; mi < 2; ++mi)
#pragma unroll
        for (int cj = 0; cj < 2; ++cj) {
            int jt16 = jt * 8 + wj * 2 + cj;
#pragma unroll
            for (int r = 0; r < 4; ++r) {
                int nloc = wm * 32 + mi * 16 + q * 4 + r;   // 0..127
                int ng = mtB * 128 + nloc;                  // 0..511
                float y0 = bf2f(Yf[yfrag(jt16, ng >> 5, ((ng >> 3) & 3) * 16 + lr)
                                   + (ng & 7)]);
                fbuf[nloc * 128 + wj * 32 + cj * 16 + lr] = acc[mi][cj][r] + y0;
            }
        }
    __syncthreads();
    float4 bv0 = *reinterpret_cast<const float4*>(bvec);
    float4 bv1 = *(reinterpret_cast<const float4*>(bvec) + 1);
#pragma unroll
    for (int i = 0; i < 4; ++i) {
        int idx = (i * 1024 + tid) * 4;          // 16384 floats
        int bb = idx >> 10, r = idx & 1023, nn = r >> 3, fo = r & 7;
        float4 v = *reinterpret_cast<const float4*>(fbuf + nn * 128 + bb * 8 + fo);
        float4 bias = (fo & 4) ? bv1 : bv0;
        v.x += bias.x; v.y += bias.y; v.z += bias.z; v.w += bias.w;
        *reinterpret_cast<float4*>(out + (size_t)(jt * 16 + bb) * 4096
                                       + (size_t)(mtB * 128 + nn) * 8 + fo) = v;
    }
}

// ---------------- last resort (tiny workspace): direct recurrence ----------------
__global__ __launch_bounds__(512, 2)
void cheb1_kernel(const float* __restrict__ x, const float* __restrict__ Lf,
                  const float* __restrict__ W, const float* __restrict__ bvec,
                  float* __restrict__ out) {
    __shared__ uint16_t ldsb[2 * ZBUF];
    uint16_t* z0 = ldsb;
    uint16_t* z1 = ldsb + ZBUF;
    const int tid = threadIdx.x, wave = tid >> 6, lane = tid & 63;
    const int lr = lane & 15, q = lane >> 4;
    const float4* x4 = reinterpret_cast<const float4*>(x + (size_t)blockIdx.x * (4 * BN * FIN));
    for (int s = 0; s < 2; ++s) {
        int a = tid + s * 512;
        int f0g = a & 3, n8 = (a >> 2) & 63, bl = a >> 8;
        int jb = bl * 2048 + n8 * 32 + f0g;
        float4 v[8];
#pragma unroll
        for (int r = 0; r < 8; ++r) v[r] = x4[jb + r * 4];
        int cb = bl * 16 + f0g * 4, nb = n8 * 8;
#pragma unroll
        for (int w = 0; w < 4; ++w) {
            frag_ab pk;
#pragma unroll
            for (int r = 0; r < 8; ++r)
                pk[r] = (short)f2bf(reinterpret_cast<const float*>(&v[r])[w]);
            *reinterpret_cast<frag_ab*>(&z0[(cb + w) * LDST + nb]) = pk;
        }
    }
    frag_ab wf[3];
#pragma unroll
    for (int p = 0; p < 3; ++p) {
        frag_ab t;
#pragma unroll
        for (int jj = 0; jj < 8; ++jj) {
            int k = q * 8 + jj, ki = p * 2 + (k >> 4), fin = k & 15;
            float val = (lr < 8 && ki < 5) ? W[ki * 128 + fin * FOUT + lr] : 0.0f;
            t[jj] = (short)f2bf(val);
        }
        wf[p] = t;
    }
    const float bv = (lr < 8) ? bvec[lr] : 0.0f;
    frag_cd accOut[4][4] = {};
    auto loadA = [&](int mt, int ks) -> frag_ab {
        const float4* p = reinterpret_cast<const float4*>(Lf + (size_t)(mt * 16 + lr) * BN + ks * 32 + q * 8);
        float4 u0 = p[0], u1 = p[1];
        frag_ab t;
        t[0] = (short)f2bf(u0.x); t[1] = (short)f2bf(u0.y);
        t[2] = (short)f2bf(u0.z); t[3] = (short)f2bf(u0.w);
        t[4] = (short)f2bf(u1.x); t[5] = (short)f2bf(u1.y);
        t[6] = (short)f2bf(u1.z); t[7] = (short)f2bf(u1.w);
        return t;
    };
    auto app = [&](const uint16_t* cur, uint16_t* dst, bool first) {
        frag_cd acc[4][4] = {};
        for (int ks = 0; ks < 16; ++ks) {
            frag_ab bfr[4];
#pragma unroll
            for (int ct = 0; ct < 4; ++ct)
                bfr[ct] = *reinterpret_cast<const frag_ab*>(
                    cur + (ct * 16 + lr) * LDST + ks * 32 + q * 8);
#pragma unroll
            for (int mi = 0; mi < 4; ++mi) {
                frag_ab a = loadA(wave + mi * 8, ks);
#pragma unroll
                for (int ct = 0; ct < 4; ++ct)
                    acc[mi][ct] = __builtin_amdgcn_mfma_f32_16x16x32_bf16(
                        a, bfr[ct], acc[mi][ct], 0, 0, 0);
            }
        }
#pragma unroll
        for (int mi = 0; mi < 4; ++mi) {
            int row0 = (wave + mi * 8) * 16 + q * 4;
#pragma unroll
            for (int ct = 0; ct < 4; ++ct) {
                uint16_t* dp = dst + (ct * 16 + lr) * LDST + row0;
                float pz[4] = {0.f, 0.f, 0.f, 0.f};
                if (!first) {
                    ushort4 pv = *reinterpret_cast<const ushort4*>(dp);
                    pz[0] = bf2f(pv.x); pz[1] = bf2f(pv.y);
                    pz[2] = bf2f(pv.z); pz[3] = bf2f(pv.w);
                }
                ushort4 nv;
                float v0 = acc[mi][ct][0], v1 = acc[mi][ct][1];
                float v2 = acc[mi][ct][2], v3 = acc[mi][ct][3];
                if (!first) { v0 = 2.f*v0-pz[0]; v1 = 2.f*v1-pz[1];
                              v2 = 2.f*v2-pz[2]; v3 = 2.f*v3-pz[3]; }
                nv.x = f2bf(v0); nv.y = f2bf(v1); nv.z = f2bf(v2); nv.w = f2bf(v3);
                *reinterpret_cast<ushort4*>(dp) = nv;
            }
        }
    };
    auto epi = [&](const uint16_t* bA, const uint16_t* bB, frag_ab wfr) {
        const uint16_t* base = (q < 2) ? bA : bB;
        int finb = (q & 1) * 8;
#pragma unroll
        for (int mi = 0; mi < 4; ++mi) {
            int n = (wave + mi * 8) * 16 + lr;
#pragma unroll
            for (int bt = 0; bt < 4; ++bt) {
                const uint16_t* pp = base + (bt * 16 + finb) * LDST + n;
                frag_ab afr;
#pragma unroll
                for (int jj = 0; jj < 8; ++jj) afr[jj] = (short)pp[jj * LDST];
                accOut[mi][bt] = __builtin_amdgcn_mfma_f32_16x16x32_bf16(
                    afr, wfr, accOut[mi][bt], 0, 0, 0);
            }
        }
    };
    __syncthreads();
    app(z0, z1, true);  __syncthreads();
    epi(z0, z1, wf[0]); __syncthreads();
    app(z1, z0, false); __syncthreads();
    app(z0, z1, false); __syncthreads();
    epi(z0, z1, wf[1]); __syncthreads();
    app(z1, z0, false); __syncthreads();
    epi(z0, z0, wf[2]);
    if (lr < 8) {
        float* ob = out + (size_t)blockIdx.x * 4 * BN * FOUT;
#pragma unroll
        for (int mi = 0; mi < 4; ++mi) {
            int row0 = (wave + mi * 8) * 16 + q * 4;
#pragma unroll
            for (int bt = 0; bt < 4; ++bt) {
                float* op = ob + bt * (BN * FOUT) + row0 * FOUT + lr;
                op[0] = accOut[mi][bt][0] + bv; op[FOUT] = accOut[mi][bt][1] + bv;
                op[2 * FOUT] = accOut[mi][bt][2] + bv; op[3 * FOUT] = accOut[mi][bt][3] + bv;
            }
        }
    }
}

extern "C" void kernel_launch(void* const* d_in, const int* in_sizes, int n_in,
                              void* d_out, int out_size, void* d_ws, size_t ws_size,
                              hipStream_t stream) {
    const float* x  = (const float*)d_in[0];   // [1024,512,16]
    const float* Lf = (const float*)d_in[1];   // [512,512]
    const float* W  = (const float*)d_in[2];   // [5,16,8]
    const float* bv = (const float*)d_in[3];   // [8]
    float* out = (float*)d_out;                // [1024,512,8]

    const size_t PCAT_B = (size_t)32 * PG * 64 * 8 * 2;    //  2,097,152
    const size_t LLO_B  = (size_t)BN * BN * 2;             //    524,288
    const size_t P2LO_B = LLO_B;                           //    524,288
    const size_t YF_B   = (size_t)512 * 80 * 64 * 8 * 2;   // 41,943,040

    if (ws_size >= PCAT_B + LLO_B + P2LO_B + YF_B) {       // 45,088,768 (known fit)
        uint16_t* Pcat = (uint16_t*)d_ws;
        uint16_t* Llo  = Pcat + PCAT_B / 2;
        uint16_t* P2lo = Pcat + (PCAT_B + LLO_B) / 2;
        uint16_t* Yf   = Pcat + (PCAT_B + LLO_B + P2LO_B) / 2;
        prepP2  <<<dim3(896), dim3(256),  0, stream>>>(x, Lf, W, Pcat, Llo, P2lo, Yf);
        p34k    <<<dim3(256), dim3(512),  0, stream>>>(Pcat, Llo, P2lo);
        chebgemm<<<dim3(256), dim3(1024), 0, stream>>>(Pcat, Yf, bv, out);
    } else {
        cheb1_kernel<<<dim3(256), dim3(512), 0, stream>>>(x, Lf, W, bv, out);
    }
}